// Round 13
// baseline (362.533 us; speedup 1.0000x reference)
//
#include <hip/hip_runtime.h>
#include <hip/hip_bf16.h>
#include <math.h>

#define F_IN 128
#define F_HID 256
#define F_OUT 10

typedef __attribute__((ext_vector_type(8))) short s16x8;
typedef __attribute__((ext_vector_type(4))) float f32x4;

static __device__ __forceinline__ float b2f(unsigned short u) {
    union { float f; unsigned int u; } c;
    c.u = ((unsigned int)u) << 16;
    return c.f;
}
static __device__ __forceinline__ unsigned short f2b(float f) {
    return __bfloat16_as_ushort(__float2bfloat16(f));
}

// ---------------- fused prep: degree count + bf16 casts ----------------
// blockIdx.y: 0=count, 1=cast x, 2=castT W1, 3=castT W2

__global__ void prep_kernel(const int* __restrict__ dst, int* __restrict__ cnt, int e,
                            const float* __restrict__ x, unsigned short* __restrict__ xb,
                            int xq,
                            const float* __restrict__ W1, unsigned short* __restrict__ W1t,
                            const float* __restrict__ W2, unsigned short* __restrict__ W2t) {
    int i = blockIdx.x * blockDim.x + threadIdx.x;
    int job = blockIdx.y;
    if (job == 0) {
        if (i < e) atomicAdd(&cnt[dst[i]], 1);
    } else if (job == 1) {
        if (i < xq) {
            float4 v = *(const float4*)&x[(size_t)i * 4];
            ushort4 o;
            o.x = f2b(v.x); o.y = f2b(v.y); o.z = f2b(v.z); o.w = f2b(v.w);
            *(ushort4*)&xb[(size_t)i * 4] = o;
        }
    } else if (job == 2) {
        if (i < F_IN * F_HID) {
            int k = i / F_HID, nn = i - k * F_HID;
            W1t[nn * F_IN + k] = f2b(W1[i]);
        }
    } else {
        if (i < F_HID * F_HID) {
            int k = i / F_HID, nn = i - k * F_HID;
            W2t[nn * F_HID + k] = f2b(W2[i]);
        }
    }
}

// ---------------- scan (rowstart) + dinv ----------------

__global__ void scan1_kernel(const int* __restrict__ cnt, int* __restrict__ rowstart,
                             int* __restrict__ partial, float* __restrict__ dinv, int n) {
    __shared__ int s[256];
    int tid = threadIdx.x;
    int i = blockIdx.x * 256 + tid;
    int v = (i < n) ? cnt[i] : 0;
    s[tid] = v;
    __syncthreads();
    for (int off = 1; off < 256; off <<= 1) {
        int t = (tid >= off) ? s[tid - off] : 0;
        __syncthreads();
        s[tid] += t;
        __syncthreads();
    }
    if (i < n) {
        rowstart[i] = s[tid] - v;                 // exclusive within block
        dinv[i] = rsqrtf((float)(v + 1));         // +1 self loop
    }
    if (tid == 255) partial[blockIdx.x] = s[255]; // block total
}

// scan2 folded in: every block re-scans the (<=256) partials in LDS, then adds its offset.
__global__ void scan3_kernel(int* __restrict__ rowstart, const int* __restrict__ partial,
                             int nb, int n, int e) {
    __shared__ int s[256];
    int tid = threadIdx.x;
    int v = (tid < nb) ? partial[tid] : 0;
    s[tid] = v;
    __syncthreads();
    for (int off = 1; off < 256; off <<= 1) {
        int t = (tid >= off) ? s[tid - off] : 0;
        __syncthreads();
        s[tid] += t;
        __syncthreads();
    }
    // exclusive offset for this block
    int boff = (blockIdx.x > 0) ? s[blockIdx.x - 1] : 0;
    __syncthreads();
    int i = blockIdx.x * 256 + tid;
    if (i < n) rowstart[i] += boff;
    if (i == 0) rowstart[n] = e;
}

__global__ void fill_kernel(const int* __restrict__ src, const int* __restrict__ dst,
                            const int* __restrict__ rowstart, int* __restrict__ cursor,
                            const float* __restrict__ dinv, int2* __restrict__ pack, int e) {
    int i = blockIdx.x * blockDim.x + threadIdx.x;
    if (i >= e) return;
    int s = src[i], d = dst[i];
    int pos = rowstart[d] + atomicAdd(&cursor[d], 1);
    float w = dinv[s] * dinv[d];
    pack[pos] = make_int2(s, __float_as_int(w));
}

// ---------------- fused aggregate + MFMA GEMM ----------------
// Block = 256 threads (4 waves), owns 64 output rows x full N=256.
// Phase 1: wave w gathers nodes bm*64+w*16 .. +15 into As[64][K+8] (bf16), using the
//          proven wave-per-node edge-group-parallel gather (K=256: 32 lanes x 2 EG;
//          K=128: 16 lanes x 4 EG), fp32 accum, unroll x4 per group.
// Phase 2: full-N MFMA (R9 anchor): Bs[256][40] staged per kstep, 16 mfma/kstep/wave.
// FUSE3=false: write relu(.@W+b) bf16 to Cb. FUSE3=true: hw3 = relu(.@W+b)@W3 in-register.

template <int K, bool FUSE3>
__global__ __launch_bounds__(256) void fused_kernel(const unsigned short* __restrict__ feat,
                                                    const int* __restrict__ rowstart,
                                                    const int2* __restrict__ pack,
                                                    const float* __restrict__ dinv,
                                                    const unsigned short* __restrict__ Bt,
                                                    const float* __restrict__ bias,
                                                    unsigned short* __restrict__ Cb,
                                                    const float* __restrict__ W3,
                                                    float* __restrict__ hw3, int M) {
    constexpr int N = F_HID;
    constexpr int KP = K + 8;  // row pad: keeps 16B alignment, spreads banks
    __shared__ unsigned short As[64][KP];
    __shared__ unsigned short Bs[N][40];
    const int tid = threadIdx.x;
    const int w = tid >> 6, lane = tid & 63;
    const int g = lane >> 4, r16 = lane & 15;
    const int bm = blockIdx.x;

    // ---- Phase 1: gather 16 nodes per wave into As ----
    {
        constexpr int LPF = K / 8;       // lanes per feature row
        constexpr int EG = 64 / LPF;     // edge groups per wave
        constexpr int STEP = EG * 4;
        const int eg = lane / LPF;
        const int fl = lane % LPF;
        const unsigned short* fp = feat + fl * 8;

        for (int i = 0; i < 16; ++i) {
            int v = bm * 64 + w * 16 + i;
            if (v >= M) break;
            float acc[8];
            {
                float d = dinv[v];
                float sw = (eg == 0) ? d * d : 0.f;
                s16x8 t = *(const s16x8*)&fp[(size_t)v * K];
#pragma unroll
                for (int j = 0; j < 8; ++j) acc[j] = sw * b2f((unsigned short)t[j]);
            }
            int e0 = rowstart[v], e1 = rowstart[v + 1];
            int e = e0;
            for (; e + STEP <= e1; e += STEP) {
                int2 p[4];
#pragma unroll
                for (int u = 0; u < 4; ++u) p[u] = pack[e + eg + u * EG];
                s16x8 t[4];
#pragma unroll
                for (int u = 0; u < 4; ++u) t[u] = *(const s16x8*)&fp[(size_t)p[u].x * K];
#pragma unroll
                for (int u = 0; u < 4; ++u) {
                    float wv = __int_as_float(p[u].y);
#pragma unroll
                    for (int j = 0; j < 8; ++j) acc[j] += wv * b2f((unsigned short)t[u][j]);
                }
            }
            for (int ee = e + eg; ee < e1; ee += EG) {
                int2 p = pack[ee];
                float wv = __int_as_float(p.y);
                s16x8 t = *(const s16x8*)&fp[(size_t)p.x * K];
#pragma unroll
                for (int j = 0; j < 8; ++j) acc[j] += wv * b2f((unsigned short)t[j]);
            }
            if (EG == 4) {
#pragma unroll
                for (int j = 0; j < 8; ++j) acc[j] += __shfl_xor(acc[j], 16);
            }
#pragma unroll
            for (int j = 0; j < 8; ++j) acc[j] += __shfl_xor(acc[j], 32);
            if (eg == 0) {
                s16x8 o;
#pragma unroll
                for (int j = 0; j < 8; ++j) o[j] = (short)f2b(acc[j]);
                *(s16x8*)&As[w * 16 + i][fl * 8] = o;
            }
        }
    }
    __syncthreads();  // As complete

    // ---- Phase 2: MFMA over ksteps, Bs staged per step ----
    f32x4 acc[16] = {};

    for (int k0 = 0; k0 < K; k0 += 32) {
        uint4 bv0 = *(const uint4*)&Bt[(size_t)tid * K + k0 + 0];
        uint4 bv1 = *(const uint4*)&Bt[(size_t)tid * K + k0 + 8];
        uint4 bv2 = *(const uint4*)&Bt[(size_t)tid * K + k0 + 16];
        uint4 bv3 = *(const uint4*)&Bt[(size_t)tid * K + k0 + 24];
        if (k0) __syncthreads();  // protect previous iteration's Bs reads
        *(uint4*)&Bs[tid][0] = bv0;
        *(uint4*)&Bs[tid][8] = bv1;
        *(uint4*)&Bs[tid][16] = bv2;
        *(uint4*)&Bs[tid][24] = bv3;
        __syncthreads();

        s16x8 af = *(const s16x8*)&As[w * 16 + r16][k0 + g * 8];
#pragma unroll
        for (int cg = 0; cg < 16; ++cg) {
            s16x8 bf = *(const s16x8*)&Bs[cg * 16 + r16][g * 8];
            acc[cg] = __builtin_amdgcn_mfma_f32_16x16x32_bf16(af, bf, acc[cg], 0, 0, 0);
        }
    }

    // C/D layout: col = cg*16 + (lane&15); row (within wave) = (lane>>4)*4 + reg
    if constexpr (!FUSE3) {
#pragma unroll
        for (int cg = 0; cg < 16; ++cg) {
            int col = cg * 16 + r16;
            float bs = bias[col];
#pragma unroll
            for (int r = 0; r < 4; ++r) {
                int row = bm * 64 + w * 16 + g * 4 + r;
                if (row < M) {
                    float v = fmaxf(acc[cg][r] + bs, 0.f);
                    Cb[(size_t)row * N + col] = f2b(v);
                }
            }
        }
    } else {
        // stage W3 [256][10] fp32 into LDS (reuse Bs region)
        float* W3s = (float*)&Bs[0][0];
        __syncthreads();  // all mfma reads of Bs done
        for (int i = tid; i < N * F_OUT; i += 256) W3s[i] = W3[i];
        __syncthreads();

        float bcol[16];
#pragma unroll
        for (int cg = 0; cg < 16; ++cg) bcol[cg] = bias[cg * 16 + r16];

#pragma unroll
        for (int r = 0; r < 4; ++r) {
            float pj[F_OUT] = {};
#pragma unroll
            for (int cg = 0; cg < 16; ++cg) {
                float v = fmaxf(acc[cg][r] + bcol[cg], 0.f);
                const float* w3r = &W3s[(cg * 16 + r16) * F_OUT];
#pragma unroll
                for (int j = 0; j < F_OUT; ++j) pj[j] += v * w3r[j];
            }
#pragma unroll
            for (int j = 0; j < F_OUT; ++j) {
                pj[j] += __shfl_xor(pj[j], 1);
                pj[j] += __shfl_xor(pj[j], 2);
                pj[j] += __shfl_xor(pj[j], 4);
                pj[j] += __shfl_xor(pj[j], 8);
            }
            if (r16 == 0) {
                int row = bm * 64 + w * 16 + g * 4 + r;
                if (row < M) {
#pragma unroll
                    for (int j = 0; j < F_OUT; ++j) hw3[(size_t)row * F_OUT + j] = pj[j];
                }
            }
        }
    }
}

// ---------------- final: 10-dim aggregation + bias + log_softmax ----------------

__global__ void final_kernel(const float* __restrict__ hw3, const int* __restrict__ rowstart,
                             const int2* __restrict__ pack, const float* __restrict__ dinv,
                             const float* __restrict__ b3, float* __restrict__ out, int n) {
    int v = blockIdx.x * blockDim.x + threadIdx.x;
    if (v >= n) return;
    float acc[F_OUT];
    float d = dinv[v];
    float sw = d * d;
#pragma unroll
    for (int j = 0; j < F_OUT; ++j) acc[j] = sw * hw3[(size_t)v * F_OUT + j];
    int e0 = rowstart[v], e1 = rowstart[v + 1];
    for (int e = e0; e < e1; ++e) {
        int2 p = pack[e];
        float w = __int_as_float(p.y);
#pragma unroll
        for (int j = 0; j < F_OUT; ++j) acc[j] += w * hw3[(size_t)p.x * F_OUT + j];
    }
#pragma unroll
    for (int j = 0; j < F_OUT; ++j) acc[j] += b3[j];
    float m = acc[0];
#pragma unroll
    for (int j = 1; j < F_OUT; ++j) m = fmaxf(m, acc[j]);
    float sum = 0.f;
#pragma unroll
    for (int j = 0; j < F_OUT; ++j) sum += expf(acc[j] - m);
    float lse = m + logf(sum);
#pragma unroll
    for (int j = 0; j < F_OUT; ++j) out[(size_t)v * F_OUT + j] = acc[j] - lse;
}

// ---------------- launch ----------------

extern "C" void kernel_launch(void* const* d_in, const int* in_sizes, int n_in,
                              void* d_out, int out_size, void* d_ws, size_t ws_size,
                              hipStream_t stream) {
    const float* x  = (const float*)d_in[0];
    const int*   ei = (const int*)d_in[1];
    const float* W1 = (const float*)d_in[2];
    const float* b1 = (const float*)d_in[3];
    const float* W2 = (const float*)d_in[4];
    const float* b2 = (const float*)d_in[5];
    const float* W3 = (const float*)d_in[6];
    const float* b3 = (const float*)d_in[7];
    float* out = (float*)d_out;

    int n = in_sizes[0] / F_IN;
    int e = in_sizes[1] / 2;
    const int* srcp = ei;
    const int* dstp = ei + e;

    size_t off = 0;
    auto alloc = [&](size_t bytes) -> char* {
        char* p = (char*)d_ws + off;
        off += (bytes + 255) & ~(size_t)255;
        return p;
    };
    size_t cntpad = ((size_t)n * 4 + 255) & ~(size_t)255;
    int*   cnt      = (int*)alloc((size_t)n * 4);
    int*   cursor   = (int*)alloc((size_t)n * 4);   // adjacent to cnt: single memset
    int*   rowstart = (int*)alloc((size_t)(n + 1) * 4);
    int*   partial  = (int*)alloc(1024 * 4);
    int2*  pack     = (int2*)alloc((size_t)e * 8);
    float* dinv     = (float*)alloc((size_t)n * 4);
    unsigned short* xb  = (unsigned short*)alloc((size_t)n * F_IN * 2);   // x bf16
    unsigned short* h1b = (unsigned short*)alloc((size_t)n * F_HID * 2);  // h1 bf16
    unsigned short* W1t = (unsigned short*)alloc((size_t)F_IN * F_HID * 2);
    unsigned short* W2t = (unsigned short*)alloc((size_t)F_HID * F_HID * 2);
    float* hw3 = (float*)alloc((size_t)n * F_OUT * 4);

    const int TB = 256;
    // one memset covers cnt + cursor (adjacent)
    hipMemsetAsync(cnt, 0, cntpad + (size_t)n * 4, stream);

    // prep: count + cast x + castT W1 + castT W2
    int xq = (int)((size_t)n * F_IN / 4);
    int prepmax = e > xq ? e : xq;
    dim3 gp((prepmax + TB - 1) / TB, 4);
    prep_kernel<<<gp, TB, 0, stream>>>(dstp, cnt, e, x, xb, xq, W1, W1t, W2, W2t);

    int nb = (n + TB - 1) / TB;
    scan1_kernel<<<nb, TB, 0, stream>>>(cnt, rowstart, partial, dinv, n);
    scan3_kernel<<<nb, TB, 0, stream>>>(rowstart, partial, nb, n, e);
    fill_kernel<<<(e + TB - 1) / TB, TB, 0, stream>>>(srcp, dstp, rowstart, cursor, dinv,
                                                      pack, e);

    int gblocks = (n + 63) / 64;

    // Layer 1 fused: gather(xb) + GEMM(W1)+bias+relu -> h1 (bf16)
    fused_kernel<F_IN, false><<<gblocks, 256, 0, stream>>>(xb, rowstart, pack, dinv,
                                                           W1t, b1, h1b, nullptr, nullptr, n);

    // Layer 2+3 fused: gather(h1) + GEMM(W2)+bias+relu + GEMM(W3) -> hw3 (fp32)
    fused_kernel<F_HID, true><<<gblocks, 256, 0, stream>>>(h1b, rowstart, pack, dinv,
                                                           W2t, b2, nullptr, W3, hw3, n);

    // final: 10-dim aggregation + bias + log_softmax
    final_kernel<<<(n + 255) / 256, 256, 0, stream>>>(hw3, rowstart, pack, dinv, b3, out, n);
}

// Round 14
// 263.061 us; speedup vs baseline: 1.3781x; 1.3781x over previous
//
#include <hip/hip_runtime.h>
#include <hip/hip_bf16.h>
#include <math.h>

#define F_IN 128
#define F_HID 256
#define F_OUT 10

typedef __attribute__((ext_vector_type(8))) short s16x8;
typedef __attribute__((ext_vector_type(4))) float f32x4;

static __device__ __forceinline__ float b2f(unsigned short u) {
    union { float f; unsigned int u; } c;
    c.u = ((unsigned int)u) << 16;
    return c.f;
}
static __device__ __forceinline__ unsigned short f2b(float f) {
    return __bfloat16_as_ushort(__float2bfloat16(f));
}

// ---------------- fused prep: degree count + bf16 casts ----------------
// blockIdx.y: 0=count, 1=cast x, 2=castT W1, 3=castT W2

__global__ void prep_kernel(const int* __restrict__ dst, int* __restrict__ cnt, int e,
                            const float* __restrict__ x, unsigned short* __restrict__ xb,
                            int xq,
                            const float* __restrict__ W1, unsigned short* __restrict__ W1t,
                            const float* __restrict__ W2, unsigned short* __restrict__ W2t) {
    int i = blockIdx.x * blockDim.x + threadIdx.x;
    int job = blockIdx.y;
    if (job == 0) {
        if (i < e) atomicAdd(&cnt[dst[i]], 1);
    } else if (job == 1) {
        if (i < xq) {
            float4 v = *(const float4*)&x[(size_t)i * 4];
            ushort4 o;
            o.x = f2b(v.x); o.y = f2b(v.y); o.z = f2b(v.z); o.w = f2b(v.w);
            *(ushort4*)&xb[(size_t)i * 4] = o;
        }
    } else if (job == 2) {
        if (i < F_IN * F_HID) {
            int k = i / F_HID, nn = i - k * F_HID;
            W1t[nn * F_IN + k] = f2b(W1[i]);
        }
    } else {
        if (i < F_HID * F_HID) {
            int k = i / F_HID, nn = i - k * F_HID;
            W2t[nn * F_HID + k] = f2b(W2[i]);
        }
    }
}

// ---------------- scan (rowstart) + dinv ----------------

__global__ void scan1_kernel(const int* __restrict__ cnt, int* __restrict__ rowstart,
                             int* __restrict__ partial, float* __restrict__ dinv, int n) {
    __shared__ int s[256];
    int tid = threadIdx.x;
    int i = blockIdx.x * 256 + tid;
    int v = (i < n) ? cnt[i] : 0;
    s[tid] = v;
    __syncthreads();
    for (int off = 1; off < 256; off <<= 1) {
        int t = (tid >= off) ? s[tid - off] : 0;
        __syncthreads();
        s[tid] += t;
        __syncthreads();
    }
    if (i < n) {
        rowstart[i] = s[tid] - v;                 // exclusive within block
        dinv[i] = rsqrtf((float)(v + 1));         // +1 self loop
    }
    if (tid == 255) partial[blockIdx.x] = s[255]; // block total
}

// scan2 folded in: every block re-scans the (<=256) partials in LDS, then adds its offset.
__global__ void scan3_kernel(int* __restrict__ rowstart, const int* __restrict__ partial,
                             int nb, int n, int e) {
    __shared__ int s[256];
    int tid = threadIdx.x;
    int v = (tid < nb) ? partial[tid] : 0;
    s[tid] = v;
    __syncthreads();
    for (int off = 1; off < 256; off <<= 1) {
        int t = (tid >= off) ? s[tid - off] : 0;
        __syncthreads();
        s[tid] += t;
        __syncthreads();
    }
    // exclusive offset for this block
    int boff = (blockIdx.x > 0) ? s[blockIdx.x - 1] : 0;
    __syncthreads();
    int i = blockIdx.x * 256 + tid;
    if (i < n) rowstart[i] += boff;
    if (i == 0) rowstart[n] = e;
}

__global__ void fill_kernel(const int* __restrict__ src, const int* __restrict__ dst,
                            const int* __restrict__ rowstart, int* __restrict__ cursor,
                            const float* __restrict__ dinv, int2* __restrict__ pack, int e) {
    int i = blockIdx.x * blockDim.x + threadIdx.x;
    if (i >= e) return;
    int s = src[i], d = dst[i];
    int pos = rowstart[d] + atomicAdd(&cursor[d], 1);
    float w = dinv[s] * dinv[d];
    pack[pos] = make_int2(s, __float_as_int(w));
}

// ---------------- aggregation: wave per node, 16B/lane, edge-group parallel ----------------
// F=256: 32 lanes/row (s16x8 each) x 2 edge-groups; F=128: 16 lanes/row x 4 groups.
// High-occupancy, zero-LDS: gather BW needs >=15 waves/CU (R13 lesson).

template <int F>
__global__ __launch_bounds__(256) void agg_kernel(const unsigned short* __restrict__ feat,
                                                  const int* __restrict__ rowstart,
                                                  const int2* __restrict__ pack,
                                                  const float* __restrict__ dinv,
                                                  unsigned short* __restrict__ out, int n) {
    constexpr int LPF = F / 8;       // lanes per feature row
    constexpr int EG = 64 / LPF;     // edge groups per wave
    int wid = threadIdx.x >> 6;
    int lane = threadIdx.x & 63;
    int v = blockIdx.x * 4 + wid;
    if (v >= n) return;
    int eg = lane / LPF;
    int fl = lane % LPF;
    const unsigned short* fp = feat + fl * 8;

    float acc[8];
    {
        float d = dinv[v];
        float sw = (eg == 0) ? d * d : 0.f;
        s16x8 t = *(const s16x8*)&fp[(size_t)v * F];
#pragma unroll
        for (int j = 0; j < 8; ++j) acc[j] = sw * b2f((unsigned short)t[j]);
    }

    int e0 = rowstart[v], e1 = rowstart[v + 1];
    constexpr int STEP = EG * 4;
    int e = e0;
    for (; e + STEP <= e1; e += STEP) {
        int2 p[4];
#pragma unroll
        for (int u = 0; u < 4; ++u) p[u] = pack[e + eg + u * EG];
        s16x8 t[4];
#pragma unroll
        for (int u = 0; u < 4; ++u) t[u] = *(const s16x8*)&fp[(size_t)p[u].x * F];
#pragma unroll
        for (int u = 0; u < 4; ++u) {
            float w = __int_as_float(p[u].y);
#pragma unroll
            for (int j = 0; j < 8; ++j) acc[j] += w * b2f((unsigned short)t[u][j]);
        }
    }
    for (int ee = e + eg; ee < e1; ee += EG) {
        int2 p = pack[ee];
        float w = __int_as_float(p.y);
        s16x8 t = *(const s16x8*)&fp[(size_t)p.x * F];
#pragma unroll
        for (int j = 0; j < 8; ++j) acc[j] += w * b2f((unsigned short)t[j]);
    }

    if (EG == 4) {
#pragma unroll
        for (int j = 0; j < 8; ++j) acc[j] += __shfl_xor(acc[j], 16);
    }
#pragma unroll
    for (int j = 0; j < 8; ++j) acc[j] += __shfl_xor(acc[j], 32);

    if (eg == 0) {
        s16x8 o;
#pragma unroll
        for (int j = 0; j < 8; ++j) o[j] = (short)f2b(acc[j]);
        *(s16x8*)&out[(size_t)v * F + fl * 8] = o;
    }
}

// ---------------- MFMA bf16 GEMM, full-N tile 64x256, LDS-staged (R9 anchor) ----------
// Stride 40 shorts (80B = 20 banks, 5 coprime 8): reads/writes bank-balanced.
// FUSE3=false: write relu(A@W+b) bf16. FUSE3=true: hw3 = relu(A@W+b)@W3 in-register.

template <int K, bool FUSE3>
__global__ __launch_bounds__(256) void gemm_kernel(const unsigned short* __restrict__ A,
                                                   const unsigned short* __restrict__ Bt,
                                                   const float* __restrict__ bias,
                                                   unsigned short* __restrict__ Cb,
                                                   const float* __restrict__ W3,
                                                   float* __restrict__ hw3, int M) {
    constexpr int N = F_HID;
    __shared__ unsigned short As[64][40];
    __shared__ unsigned short Bs[N][40];
    const int tid = threadIdx.x;
    const int w = tid >> 6, lane = tid & 63;
    const int g = lane >> 4, r16 = lane & 15;
    const int bm = blockIdx.x;

    const int sArow = tid >> 2;
    const int sAkq = (tid & 3) * 8;
    const int garow = bm * 64 + sArow;

    f32x4 acc[16] = {};

    for (int k0 = 0; k0 < K; k0 += 32) {
        uint4 av = make_uint4(0, 0, 0, 0);
        if (garow < M) av = *(const uint4*)&A[(size_t)garow * K + k0 + sAkq];
        uint4 bv0 = *(const uint4*)&Bt[(size_t)tid * K + k0 + 0];
        uint4 bv1 = *(const uint4*)&Bt[(size_t)tid * K + k0 + 8];
        uint4 bv2 = *(const uint4*)&Bt[(size_t)tid * K + k0 + 16];
        uint4 bv3 = *(const uint4*)&Bt[(size_t)tid * K + k0 + 24];
        __syncthreads();   // protect previous iteration's LDS reads
        *(uint4*)&As[sArow][sAkq] = av;
        *(uint4*)&Bs[tid][0] = bv0;
        *(uint4*)&Bs[tid][8] = bv1;
        *(uint4*)&Bs[tid][16] = bv2;
        *(uint4*)&Bs[tid][24] = bv3;
        __syncthreads();

        s16x8 af = *(const s16x8*)&As[w * 16 + r16][g * 8];
#pragma unroll
        for (int cg = 0; cg < 16; ++cg) {
            s16x8 bf = *(const s16x8*)&Bs[cg * 16 + r16][g * 8];
            acc[cg] = __builtin_amdgcn_mfma_f32_16x16x32_bf16(af, bf, acc[cg], 0, 0, 0);
        }
    }

    // C/D layout: col = cg*16 + (lane&15); row (within wave) = (lane>>4)*4 + reg
    if constexpr (!FUSE3) {
#pragma unroll
        for (int cg = 0; cg < 16; ++cg) {
            int col = cg * 16 + r16;
            float bs = bias[col];
#pragma unroll
            for (int r = 0; r < 4; ++r) {
                int row = bm * 64 + w * 16 + g * 4 + r;
                if (row < M) {
                    float v = fmaxf(acc[cg][r] + bs, 0.f);
                    Cb[(size_t)row * N + col] = f2b(v);
                }
            }
        }
    } else {
        // stage W3 [256][10] fp32 into LDS (reuse Bs region)
        float* W3s = (float*)&Bs[0][0];
        __syncthreads();
        for (int i = tid; i < N * F_OUT; i += 256) W3s[i] = W3[i];
        __syncthreads();

        float bcol[16];
#pragma unroll
        for (int cg = 0; cg < 16; ++cg) bcol[cg] = bias[cg * 16 + r16];

#pragma unroll
        for (int r = 0; r < 4; ++r) {
            float pj[F_OUT] = {};
#pragma unroll
            for (int cg = 0; cg < 16; ++cg) {
                float v = fmaxf(acc[cg][r] + bcol[cg], 0.f);
                const float* w3r = &W3s[(cg * 16 + r16) * F_OUT];
#pragma unroll
                for (int j = 0; j < F_OUT; ++j) pj[j] += v * w3r[j];
            }
#pragma unroll
            for (int j = 0; j < F_OUT; ++j) {
                pj[j] += __shfl_xor(pj[j], 1);
                pj[j] += __shfl_xor(pj[j], 2);
                pj[j] += __shfl_xor(pj[j], 4);
                pj[j] += __shfl_xor(pj[j], 8);
            }
            if (r16 == 0) {
                int row = bm * 64 + w * 16 + g * 4 + r;
                if (row < M) {
#pragma unroll
                    for (int j = 0; j < F_OUT; ++j) hw3[(size_t)row * F_OUT + j] = pj[j];
                }
            }
        }
    }
}

// ---------------- final: 10-dim aggregation + bias + log_softmax ----------------

__global__ void final_kernel(const float* __restrict__ hw3, const int* __restrict__ rowstart,
                             const int2* __restrict__ pack, const float* __restrict__ dinv,
                             const float* __restrict__ b3, float* __restrict__ out, int n) {
    int v = blockIdx.x * blockDim.x + threadIdx.x;
    if (v >= n) return;
    float acc[F_OUT];
    float d = dinv[v];
    float sw = d * d;
#pragma unroll
    for (int j = 0; j < F_OUT; ++j) acc[j] = sw * hw3[(size_t)v * F_OUT + j];
    int e0 = rowstart[v], e1 = rowstart[v + 1];
    for (int e = e0; e < e1; ++e) {
        int2 p = pack[e];
        float w = __int_as_float(p.y);
#pragma unroll
        for (int j = 0; j < F_OUT; ++j) acc[j] += w * hw3[(size_t)p.x * F_OUT + j];
    }
#pragma unroll
    for (int j = 0; j < F_OUT; ++j) acc[j] += b3[j];
    float m = acc[0];
#pragma unroll
    for (int j = 1; j < F_OUT; ++j) m = fmaxf(m, acc[j]);
    float sum = 0.f;
#pragma unroll
    for (int j = 0; j < F_OUT; ++j) sum += expf(acc[j] - m);
    float lse = m + logf(sum);
#pragma unroll
    for (int j = 0; j < F_OUT; ++j) out[(size_t)v * F_OUT + j] = acc[j] - lse;
}

// ---------------- launch ----------------

extern "C" void kernel_launch(void* const* d_in, const int* in_sizes, int n_in,
                              void* d_out, int out_size, void* d_ws, size_t ws_size,
                              hipStream_t stream) {
    const float* x  = (const float*)d_in[0];
    const int*   ei = (const int*)d_in[1];
    const float* W1 = (const float*)d_in[2];
    const float* b1 = (const float*)d_in[3];
    const float* W2 = (const float*)d_in[4];
    const float* b2 = (const float*)d_in[5];
    const float* W3 = (const float*)d_in[6];
    const float* b3 = (const float*)d_in[7];
    float* out = (float*)d_out;

    int n = in_sizes[0] / F_IN;
    int e = in_sizes[1] / 2;
    const int* srcp = ei;
    const int* dstp = ei + e;

    size_t off = 0;
    auto alloc = [&](size_t bytes) -> char* {
        char* p = (char*)d_ws + off;
        off += (bytes + 255) & ~(size_t)255;
        return p;
    };
    size_t cntpad = ((size_t)n * 4 + 255) & ~(size_t)255;
    int*   cnt      = (int*)alloc((size_t)n * 4);
    int*   cursor   = (int*)alloc((size_t)n * 4);   // adjacent to cnt: single memset
    int*   rowstart = (int*)alloc((size_t)(n + 1) * 4);
    int*   partial  = (int*)alloc(1024 * 4);
    int2*  pack     = (int2*)alloc((size_t)e * 8);
    float* dinv     = (float*)alloc((size_t)n * 4);
    unsigned short* xb   = (unsigned short*)alloc((size_t)n * F_IN * 2);   // x bf16
    unsigned short* aggb = (unsigned short*)alloc((size_t)n * F_HID * 2);  // agg out bf16
    unsigned short* h1b  = (unsigned short*)alloc((size_t)n * F_HID * 2);  // h1 bf16
    unsigned short* W1t  = (unsigned short*)alloc((size_t)F_IN * F_HID * 2);
    unsigned short* W2t  = (unsigned short*)alloc((size_t)F_HID * F_HID * 2);
    float* hw3 = (float*)alloc((size_t)n * F_OUT * 4);

    const int TB = 256;
    // one memset covers cnt + cursor (adjacent)
    hipMemsetAsync(cnt, 0, cntpad + (size_t)n * 4, stream);

    // prep: count + cast x + castT W1 + castT W2
    int xq = (int)((size_t)n * F_IN / 4);
    int prepmax = e > xq ? e : xq;
    dim3 gp((prepmax + TB - 1) / TB, 4);
    prep_kernel<<<gp, TB, 0, stream>>>(dstp, cnt, e, x, xb, xq, W1, W1t, W2, W2t);

    int nb = (n + TB - 1) / TB;
    scan1_kernel<<<nb, TB, 0, stream>>>(cnt, rowstart, partial, dinv, n);
    scan3_kernel<<<nb, TB, 0, stream>>>(rowstart, partial, nb, n, e);
    fill_kernel<<<(e + TB - 1) / TB, TB, 0, stream>>>(srcp, dstp, rowstart, cursor, dinv,
                                                      pack, e);

    int nwave = (n + 3) / 4;
    int gblocks = (n + 63) / 64;

    // Layer 1: aggregate x_bf16 (128) -> aggb, GEMM+bias+relu -> h1 (bf16)
    agg_kernel<F_IN><<<nwave, 256, 0, stream>>>(xb, rowstart, pack, dinv, aggb, n);
    gemm_kernel<F_IN, false><<<gblocks, 256, 0, stream>>>(aggb, W1t, b1, h1b, nullptr, nullptr, n);

    // Layer 2: aggregate h1_bf16 (256) -> aggb, fused GEMM2+relu+GEMM3 -> hw3 (fp32)
    agg_kernel<F_HID><<<nwave, 256, 0, stream>>>(h1b, rowstart, pack, dinv, aggb, n);
    gemm_kernel<F_HID, true><<<gblocks, 256, 0, stream>>>(aggb, W2t, b2, nullptr, W3, hw3, n);

    // final: 10-dim aggregation + bias + log_softmax
    final_kernel<<<(n + 255) / 256, 256, 0, stream>>>(hw3, rowstart, pack, dinv, b3, out, n);
}